// Round 1
// baseline (489.762 us; speedup 1.0000x reference)
//
#include <hip/hip_runtime.h>
#include <hip/hip_bf16.h>
#include <math.h>

// PCNN fused: Conv1d(k=3,pad=1) -> masked piecewise max-pool -> tanh
// R9: channel-chunk streamed pipeline.
//  - K reordered (kc-major, tap-minor): chunk = 32 channels x 130 halo rows.
//  - 5-slot LDS ring (slot == kc), stage chunk g+2 while computing chunk g,
//    T14 split (issue loads early / cvt+ds_write late), 1 barrier per chunk.
//  - Quasi-persistent blocks: IB=4 batches per block, grid 512 = 2 blocks/CU.
//  - CS=40 shorts (80B) row stride: uniform bank usage for ds_read_b128;
//    halo rows 0/129 physically present & zeroed once (no divergent remap).

#define B_SZ   2048
#define L_SEQ  128
#define C_INCH 150
#define H_OUT  230

#define IB     4               // batches per block
#define CS     40              // shorts per chunk row (80 B, 16B-aligned)
#define NR     130             // rows 0..129 (0 and 129 = zero halo)
#define SLOT   (NR * CS)       // 5200 shorts = 10400 B per ring slot

typedef __attribute__((ext_vector_type(8))) short short8;   // 8 bf16
typedef __attribute__((ext_vector_type(4))) float float4v;  // mfma acc

static __device__ __forceinline__ unsigned short f2bf(float f) {
    union { float f; unsigned u; } x{f};
    unsigned r = (x.u + 0x7FFFu + ((x.u >> 16) & 1u)) >> 16;  // RNE
    return (unsigned short)r;
}

static __device__ __forceinline__ unsigned cvt2(float2 f) {
    __hip_bfloat162 h = __float22bfloat162_rn(f);   // v_cvt_pk_bf16_f32
    union { __hip_bfloat162 h; unsigned u; } c{h};
    return c.u;
}

static __device__ __forceinline__ float tanh_fast_pos(float v) {
    float e = __expf(2.0f * v);
    return 1.0f - 2.0f / (e + 1.0f);
}

// Pack W[h][c][k] fp32 -> Wpk fragment order (same lane/e layout as verified
// R4-R8, but fragment index reordered: kk = kc*3 + k  (was k*5 + kc)):
//   ht = h/16, lane = q*16+c15
//   Wpk[((kk*16+ht)*64+lane)*8 + e] = bf16(W[ht*16+c15][kc*32+q*8+e][k])
__global__ void pack_w_kernel(const float* __restrict__ W,
                              unsigned short* __restrict__ Wpk) {
    int t = blockIdx.x * 256 + threadIdx.x;       // < 15360
    int kk   = t >> 10;
    int rem  = t & 1023;
    int ht   = rem >> 6;
    int lane = rem & 63;
    int q    = lane >> 4;
    int c15  = lane & 15;
    int kc   = kk / 3;                  // channel block 0..4
    int k    = kk - kc * 3;             // tap 0..2
    int h    = ht * 16 + c15;
    int cb   = kc * 32 + q * 8;
    unsigned short v[8];
    #pragma unroll
    for (int e = 0; e < 8; ++e) {
        int c = cb + e;
        float f = (h < H_OUT && c < C_INCH) ? W[h * 450 + c * 3 + k] : 0.0f;
        v[e] = f2bf(f);
    }
    *(short8*)(Wpk + (size_t)t * 8) = *(short8*)v;
}

__global__ void __launch_bounds__(512, 4)
pcnn_mfma(const float* __restrict__ Xea, const int* __restrict__ Xmask,
          const unsigned short* __restrict__ Wpk,
          const float* __restrict__ bias, float* __restrict__ out) {
    __shared__ __align__(16) unsigned short sX[5 * SLOT];    // 52000 B ring
    __shared__ __align__(16) float sSel[2][L_SEQ * 3];       // 3072 B (dbuf)
    __shared__ __align__(16) float sP[512 * 3];              // 6144 B partials

    const int tid  = threadIdx.x;
    const int lane = tid & 63;
    const int wv   = tid >> 6;        // 0..7
    const int q    = lane >> 4;
    const int c15  = lane & 15;
    const int mh   = wv & 1;          // m-half: l offset 64*mh
    const int nh   = wv >> 1;         // n-quarter: h offset 64*nh
    const int b0   = blockIdx.x * IB;

    // staging thread mapping: one 8-float row segment per thread per chunk
    const int sr = tid >> 2;          // row 0..127
    const int sg = tid & 3;           // segment (cols sg*8..sg*8+7 of chunk)

    const unsigned short* wp = Wpk + ((size_t)(nh * 4) * 64 + lane) * 8;

    // ---- zero halo rows (rows 0 and 129) of all 5 slots, once ----
    if (tid < 50) {
        const int sl = tid / 10, w = tid - sl * 10;
        const int row = (w < 5) ? 0 : 129;
        const int j   = (w < 5) ? w : w - 5;
        uint4 z{0u, 0u, 0u, 0u};
        *(uint4*)(sX + sl * SLOT + row * CS + j * 8) = z;
    }

    // ---- prologue: stage (b0,kc=0)->slot0, (b0,kc=1)->slot1; sSel[0] ----
    {
        const float* xp = Xea + (size_t)(b0 * L_SEQ + sr) * C_INCH;
        const float2* p0 = (const float2*)(xp + sg * 8);          // kc=0
        float2 f0 = p0[0], f1 = p0[1], f2 = p0[2], f3 = p0[3];
        uint4 u0{cvt2(f0), cvt2(f1), cvt2(f2), cvt2(f3)};
        *(uint4*)(sX + (sr + 1) * CS + sg * 8) = u0;
        const float2* p1 = (const float2*)(xp + 32 + sg * 8);     // kc=1
        f0 = p1[0]; f1 = p1[1]; f2 = p1[2]; f3 = p1[3];
        uint4 u1{cvt2(f0), cvt2(f1), cvt2(f2), cvt2(f3)};
        *(uint4*)(sX + SLOT + (sr + 1) * CS + sg * 8) = u1;
    }
    if (tid < L_SEQ) {
        const int mv = Xmask[(size_t)b0 * L_SEQ + tid];
        sSel[0][tid * 3 + 0] = (mv == 1) ? 0.0f : -1e30f;
        sSel[0][tid * 3 + 1] = (mv == 2) ? 0.0f : -1e30f;
        sSel[0][tid * 3 + 2] = (mv == 3) ? 0.0f : -1e30f;
    }

    short8 bc[4], bn[4];
    #pragma unroll
    for (int nj = 0; nj < 4; ++nj)
        bc[nj] = *(const short8*)(wp + nj * 512);                 // frag 0

    float4v acc[4][4];
    #pragma unroll
    for (int mi = 0; mi < 4; ++mi)
        #pragma unroll
        for (int nj = 0; nj < 4; ++nj)
            acc[mi][nj] = (float4v){0.f, 0.f, 0.f, 0.f};

    __syncthreads();

    for (int bl = 0; bl < IB; ++bl) {
        const int b = b0 + bl;
        const bool nb = (bl + 1 < IB);

        #pragma unroll
        for (int kc = 0; kc < 5; ++kc) {
            // ---- stage issue: chunk 2 ahead (same b: kc+2; next b: kc-3) ----
            const bool stNext = (kc >= 3);
            const bool doSt   = stNext ? nb : true;
            const int  skc    = stNext ? (kc - 3) : (kc + 2);     // == slot
            float2 f0{0.f,0.f}, f1{0.f,0.f}, f2{0.f,0.f}, f3{0.f,0.f};
            if (doSt) {
                const int sb = stNext ? (b + 1) : b;
                const float2* p = (const float2*)(
                    Xea + (size_t)(sb * L_SEQ + sr) * C_INCH + skc * 32 + sg * 8);
                if (skc < 4 || sg < 2) { f0 = p[0]; f1 = p[1]; f2 = p[2]; f3 = p[3]; }
                else if (sg == 2)      { f0 = p[0]; f1 = p[1]; f2 = p[2]; }
                // skc==4, sg==3: channels 152..159 don't exist -> stay zero
                // skc==4, sg==2: cols 144..149 real, 150/151 stay zero
            }
            int mv = 0;
            if (kc == 3 && nb && tid < L_SEQ)
                mv = Xmask[(size_t)(b + 1) * L_SEQ + tid];

            // ---- compute chunk (b, kc) from ring slot kc ----
            // buffer row rr = l + k  (rr holds X row rr-1; rr 0/129 are zeros)
            const unsigned short* ap =
                sX + kc * SLOT + (mh * 64 + c15) * CS + q * 8;
            #pragma unroll
            for (int k = 0; k < 3; ++k) {
                const int f  = kc * 3 + k;
                const int fn = (f + 1 < 15) ? (f + 1) : 0;
                #pragma unroll
                for (int nj = 0; nj < 4; ++nj)
                    bn[nj] = *(const short8*)(wp + fn * 8192 + nj * 512);
                short8 a[4];
                #pragma unroll
                for (int mi = 0; mi < 4; ++mi)
                    a[mi] = *(const short8*)(ap + (mi * 16 + k) * CS);
                #pragma unroll
                for (int mi = 0; mi < 4; ++mi)
                    #pragma unroll
                    for (int nj = 0; nj < 4; ++nj)
                        acc[mi][nj] = __builtin_amdgcn_mfma_f32_16x16x32_bf16(
                            a[mi], bc[nj], acc[mi][nj], 0, 0, 0);
                #pragma unroll
                for (int nj = 0; nj < 4; ++nj) bc[nj] = bn[nj];
            }

            // ---- epilogue A (last chunk of b): pooled partials -> sP ----
            if (kc == 4) {
                float pz[4][3];
                #pragma unroll
                for (int nj = 0; nj < 4; ++nj) {
                    pz[nj][0] = -1e30f; pz[nj][1] = -1e30f; pz[nj][2] = -1e30f;
                }
                const float* selB = sSel[bl & 1];
                #pragma unroll
                for (int mi = 0; mi < 4; ++mi) {
                    const int l0 = mh * 64 + mi * 16 + q * 4;       // mult of 4
                    const float4v* sp_ = (const float4v*)(selB + l0 * 3);
                    const float4v s0 = sp_[0], s1 = sp_[1], s2 = sp_[2];
                    const float sl[12] = {s0.x, s0.y, s0.z, s0.w, s1.x, s1.y,
                                          s1.z, s1.w, s2.x, s2.y, s2.z, s2.w};
                    #pragma unroll
                    for (int nj = 0; nj < 4; ++nj)
                        #pragma unroll
                        for (int r = 0; r < 4; ++r) {
                            const float y = acc[mi][nj][r];
                            pz[nj][0] = fmaxf(pz[nj][0], y + sl[r * 3 + 0]);
                            pz[nj][1] = fmaxf(pz[nj][1], y + sl[r * 3 + 1]);
                            pz[nj][2] = fmaxf(pz[nj][2], y + sl[r * 3 + 2]);
                        }
                }
                #pragma unroll
                for (int mi = 0; mi < 4; ++mi)
                    #pragma unroll
                    for (int nj = 0; nj < 4; ++nj)
                        acc[mi][nj] = (float4v){0.f, 0.f, 0.f, 0.f};
                #pragma unroll
                for (int nj = 0; nj < 4; ++nj) {
                    float p0 = pz[nj][0], p1 = pz[nj][1], p2 = pz[nj][2];
                    p0 = fmaxf(p0, __shfl_xor(p0, 16, 64));
                    p1 = fmaxf(p1, __shfl_xor(p1, 16, 64));
                    p2 = fmaxf(p2, __shfl_xor(p2, 16, 64));
                    p0 = fmaxf(p0, __shfl_xor(p0, 32, 64));
                    p1 = fmaxf(p1, __shfl_xor(p1, 32, 64));
                    p2 = fmaxf(p2, __shfl_xor(p2, 32, 64));
                    if (q == 0) {
                        const int hl = nh * 64 + nj * 16 + c15;     // 0..255
                        float* d = sP + (mh * 256 + hl) * 3;
                        d[0] = p0; d[1] = p1; d[2] = p2;
                    }
                }
            }

            // ---- stage write (cvt late; loads covered by compute above) ----
            if (doSt) {
                uint4 u{cvt2(f0), cvt2(f1), cvt2(f2), cvt2(f3)};
                *(uint4*)(sX + skc * SLOT + (sr + 1) * CS + sg * 8) = u;
            }
            if (kc == 3 && nb && tid < L_SEQ) {
                float* s_ = sSel[(bl + 1) & 1] + tid * 3;
                s_[0] = (mv == 1) ? 0.0f : -1e30f;
                s_[1] = (mv == 2) ? 0.0f : -1e30f;
                s_[2] = (mv == 3) ? 0.0f : -1e30f;
            }

            __syncthreads();

            // ---- epilogue B: combine m-halves, bias, tanh, store ----
            if (kc == 4) {
                for (int t = tid; t < 768; t += 512) {
                    const int h = t / 3;
                    const int p = t - h * 3;
                    if (h < H_OUT) {
                        float v = fmaxf(sP[h * 3 + p], sP[(256 + h) * 3 + p]);
                        v = fmaxf(0.0f, v + bias[h]);
                        out[(size_t)b * (3 * H_OUT) + h * 3 + p] =
                            tanh_fast_pos(v);
                    }
                }
            }
        }
    }
}

extern "C" void kernel_launch(void* const* d_in, const int* in_sizes, int n_in,
                              void* d_out, int out_size, void* d_ws, size_t ws_size,
                              hipStream_t stream) {
    const float* Xea   = (const float*)d_in[0];   // [2048,128,150] f32
    const int*   Xmask = (const int*)d_in[1];     // [2048,128] i32
    const float* W     = (const float*)d_in[2];   // [230,150,3] f32
    const float* bias  = (const float*)d_in[3];   // [230] f32
    float* out = (float*)d_out;                   // [2048,690] f32
    unsigned short* Wpk = (unsigned short*)d_ws;  // 245760 B

    pack_w_kernel<<<60, 256, 0, stream>>>(W, Wpk);
    pcnn_mfma<<<B_SZ / IB, 512, 0, stream>>>(Xea, Xmask, Wpk, bias, out);
}

// Round 2
// 294.548 us; speedup vs baseline: 1.6628x; 1.6628x over previous
//
#include <hip/hip_runtime.h>
#include <hip/hip_bf16.h>
#include <math.h>

// PCNN fused: Conv1d(k=3,pad=1) -> masked piecewise max-pool -> tanh
// R10: revert to verified R8 memory pattern (contiguous per-batch staging,
//      monolithic tile); raise concurrency instead of intra-block pipelining.
//  - Block = 4 waves (256 thr) = one batch x one H-half (128 of 256 padded).
//  - 4 blocks/CU (LDS 40960*4 = 160 KiB exactly; regs 64 VGPR + 64 AGPR = 128
//    = launch_bounds(256,4) cap) -> staging walls overlap across 4 blocks.
//  - The two n-half blocks of a batch are paired onto the same XCD and
//    adjacent dispatch slots so the duplicated X stage hits L2.
//  - K-loop / W-pack / halo remap / epilogue logic identical to verified R8.

#define B_SZ   2048
#define L_SEQ  128
#define C_INCH 150
#define H_OUT  230
#define RS     152      // row stride in bf16 (304 B); 152 = 19*8
#define NROW   129      // rows l=-1..127; l=128 halo remapped to row 0 (both zero)
#define NS8    2451     // short8s per tile = NROW*RS/8

typedef __attribute__((ext_vector_type(8))) short short8;   // 8 bf16
typedef __attribute__((ext_vector_type(4))) float float4v;  // mfma acc

static __device__ __forceinline__ unsigned short f2bf(float f) {
    union { float f; unsigned u; } x{f};
    unsigned r = (x.u + 0x7FFFu + ((x.u >> 16) & 1u)) >> 16;  // RNE
    return (unsigned short)r;
}

static __device__ __forceinline__ unsigned cvt2(float2 f) {
    __hip_bfloat162 h = __float22bfloat162_rn(f);   // v_cvt_pk_bf16_f32
    union { __hip_bfloat162 h; unsigned u; } c{h};
    return c.u;
}

static __device__ __forceinline__ float tanh_fast_pos(float v) {
    float e = __expf(2.0f * v);
    return 1.0f - 2.0f / (e + 1.0f);
}

// Pack W[h][c][k] fp32 -> Wpk fragment order (verified R4-R8):
//   kk = k*5+kc, ht = h/16, lane = q*16+c15
//   Wpk[((kk*16+ht)*64+lane)*8 + e] = bf16(W[ht*16+c15][kc*32+q*8+e][k])
__global__ void pack_w_kernel(const float* __restrict__ W,
                              unsigned short* __restrict__ Wpk) {
    int t = blockIdx.x * 256 + threadIdx.x;       // < 15360
    int kk   = t >> 10;
    int rem  = t & 1023;
    int ht   = rem >> 6;
    int lane = rem & 63;
    int q    = lane >> 4;
    int c15  = lane & 15;
    int k    = kk / 5;
    int kc   = kk - k * 5;
    int h    = ht * 16 + c15;
    int cb   = kc * 32 + q * 8;
    unsigned short v[8];
    #pragma unroll
    for (int e = 0; e < 8; ++e) {
        int c = cb + e;
        float f = (h < H_OUT && c < C_INCH) ? W[h * 450 + c * 3 + k] : 0.0f;
        v[e] = f2bf(f);
    }
    *(short8*)(Wpk + (size_t)t * 8) = *(short8*)v;
}

__global__ void __launch_bounds__(256, 4)
pcnn_mfma(const float* __restrict__ Xea, const int* __restrict__ Xmask,
          const unsigned short* __restrict__ Wpk,
          const float* __restrict__ bias, float* __restrict__ out) {
    __shared__ __align__(16) unsigned short sX[NROW * RS];   // 39216 B
    __shared__ __align__(16) float sSel[L_SEQ * 3];          // 1536 B (tot 40752)

    const int tid  = threadIdx.x;
    const int wv   = tid >> 6;        // 0..3
    const int lane = tid & 63;
    const int q    = lane >> 4;
    const int c15  = lane & 15;
    const int mh   = wv & 1;          // m-half: l offset 64*mh
    const int nh   = wv >> 1;         // n-eighth within half: h offset 64*nh (0..1)

    // batch / n-half decode: pair the two halves of a batch on one XCD,
    // adjacent dispatch slots (g = xcd + 8*(2*loc + nb)).
    const int g    = blockIdx.x;
    const int xcd  = g & 7;
    const int rest = g >> 3;          // 0..511
    const int b    = xcd * 256 + (rest >> 1);
    const int nb   = rest & 1;        // H-half: 0 -> h 0..127, 1 -> h 128..229

    // ---- Fused staging: fp32 global -> bf16 LDS, one short8/thread-iter ----
    // t indexes short8s: row = t/19 (l = row-1), j = t%19 covers cols 8j..8j+7.
    // row 0 = zero halo (serves l=-1 and remapped l=128). Cols 150,151 zero.
    const float* xb = Xea + (size_t)b * (L_SEQ * C_INCH);
    #pragma unroll
    for (int it = 0; it < 10; ++it) {
        const int t = it * 256 + tid;
        if (it < 9 || t < NS8) {
            const int row = t / 19;
            const int j   = t - row * 19;
            float2 f0 = {0.f, 0.f}, f1 = {0.f, 0.f}, f2 = {0.f, 0.f}, f3 = {0.f, 0.f};
            if (row > 0) {
                const float2* src = (const float2*)(xb + (row - 1) * C_INCH + j * 8);
                f0 = src[0];
                f1 = src[1];
                f2 = src[2];
                if (j < 18) f3 = src[3];            // j=18: cols 150,151 stay 0
            }
            uint4 u;
            u.x = cvt2(f0); u.y = cvt2(f1); u.z = cvt2(f2); u.w = cvt2(f3);
            *(uint4*)(sX + (size_t)t * 8) = u;
        }
    }

    // mask -> piece selectors {0, -1e30}
    if (tid < L_SEQ) {
        int mv = Xmask[(size_t)b * L_SEQ + tid];
        sSel[tid * 3 + 0] = (mv == 1) ? 0.0f : -1e30f;
        sSel[tid * 3 + 1] = (mv == 2) ? 0.0f : -1e30f;
        sSel[tid * 3 + 2] = (mv == 3) ? 0.0f : -1e30f;
    }

    // first B frags in flight before the barrier (independent of LDS)
    const unsigned short* wp = Wpk + ((size_t)(nb * 8 + nh * 4) * 64 + lane) * 8;
    short8 bc[4], bn[4];
    #pragma unroll
    for (int nj = 0; nj < 4; ++nj)
        bc[nj] = *(const short8*)(wp + nj * 512);

    __syncthreads();

    // ---- MFMA: 15 K-chunks of 32, B double-buffered from L2 ----
    float4v acc[4][4];
    #pragma unroll
    for (int mi = 0; mi < 4; ++mi)
        #pragma unroll
        for (int nj = 0; nj < 4; ++nj)
            acc[mi][nj] = (float4v){0.f, 0.f, 0.f, 0.f};

    const unsigned short* a0p = sX + (mh * 64 + c15) * RS + q * 8;
    // l=128 halo: row mh*64+c15+mi*16+k == 129 only at (mh=1,mi=3,c15=15,k=2);
    // remap to row 0 (zeros).
    const unsigned short* a3p2 = (mh == 1 && c15 == 15) ? (a0p - 129 * RS) : a0p;

    #pragma unroll
    for (int kk = 0; kk < 15; ++kk) {
        const int k  = kk / 5;
        const int kc = kk - k * 5;
        if (kk < 14) {
            #pragma unroll
            for (int nj = 0; nj < 4; ++nj)
                bn[nj] = *(const short8*)(wp + (kk + 1) * 8192 + nj * 512);
        }
        short8 a[4];
        #pragma unroll
        for (int mi = 0; mi < 4; ++mi) {
            const unsigned short* base = (mi == 3 && k == 2) ? a3p2 : a0p;
            a[mi] = *(const short8*)(base + (mi * 16 + k) * RS + kc * 32);
        }
        #pragma unroll
        for (int mi = 0; mi < 4; ++mi)
            #pragma unroll
            for (int nj = 0; nj < 4; ++nj)
                acc[mi][nj] = __builtin_amdgcn_mfma_f32_16x16x32_bf16(
                    a[mi], bc[nj], acc[mi][nj], 0, 0, 0);
        #pragma unroll
        for (int nj = 0; nj < 4; ++nj)
            bc[nj] = bn[nj];
    }

    // ---- Epilogue: selector-add masked max (bias deferred) ----
    // C/D layout: col(h)=c15, row(l in frag)=q*4+r
    float pz[4][3];
    #pragma unroll
    for (int nj = 0; nj < 4; ++nj)
        #pragma unroll
        for (int p = 0; p < 3; ++p) pz[nj][p] = -1e30f;

    #pragma unroll
    for (int mi = 0; mi < 4; ++mi) {
        const int l0 = mh * 64 + mi * 16 + q * 4;            // mult of 4
        const float4v* sp = (const float4v*)(sSel + l0 * 3); // 48B, 16B-aligned
        const float4v s0 = sp[0], s1 = sp[1], s2 = sp[2];
        const float sl[12] = {s0.x, s0.y, s0.z, s0.w, s1.x, s1.y,
                              s1.z, s1.w, s2.x, s2.y, s2.z, s2.w};
        #pragma unroll
        for (int nj = 0; nj < 4; ++nj)
            #pragma unroll
            for (int r = 0; r < 4; ++r) {
                const float y = acc[mi][nj][r];
                pz[nj][0] = fmaxf(pz[nj][0], y + sl[r * 3 + 0]);
                pz[nj][1] = fmaxf(pz[nj][1], y + sl[r * 3 + 1]);
                pz[nj][2] = fmaxf(pz[nj][2], y + sl[r * 3 + 2]);
            }
    }

    __syncthreads();   // all sX reads done -> alias partials onto sX
    float* sP = (float*)sX;   // [mh][hl 0..127][3] = 768 floats

    #pragma unroll
    for (int nj = 0; nj < 4; ++nj) {
        float p0 = pz[nj][0], p1 = pz[nj][1], p2 = pz[nj][2];
        p0 = fmaxf(p0, __shfl_xor(p0, 16, 64));
        p1 = fmaxf(p1, __shfl_xor(p1, 16, 64));
        p2 = fmaxf(p2, __shfl_xor(p2, 16, 64));
        p0 = fmaxf(p0, __shfl_xor(p0, 32, 64));
        p1 = fmaxf(p1, __shfl_xor(p1, 32, 64));
        p2 = fmaxf(p2, __shfl_xor(p2, 32, 64));
        if (q == 0) {
            const int hl = nh * 64 + nj * 16 + c15;          // 0..127
            float* d = sP + (mh * 128 + hl) * 3;
            d[0] = p0; d[1] = p1; d[2] = p2;
        }
    }
    __syncthreads();

    // Combine m-halves, add bias, clamp 0, tanh, store (this block's H-half)
    for (int t = tid; t < 384; t += 256) {
        const int hl = t / 3;
        const int p  = t - hl * 3;
        const int h  = nb * 128 + hl;
        if (h < H_OUT) {
            float v = fmaxf(sP[hl * 3 + p], sP[(128 + hl) * 3 + p]);
            v = fmaxf(0.0f, v + bias[h]);
            out[(size_t)b * (3 * H_OUT) + h * 3 + p] = tanh_fast_pos(v);
        }
    }
}

extern "C" void kernel_launch(void* const* d_in, const int* in_sizes, int n_in,
                              void* d_out, int out_size, void* d_ws, size_t ws_size,
                              hipStream_t stream) {
    const float* Xea   = (const float*)d_in[0];   // [2048,128,150] f32
    const int*   Xmask = (const int*)d_in[1];     // [2048,128] i32
    const float* W     = (const float*)d_in[2];   // [230,150,3] f32
    const float* bias  = (const float*)d_in[3];   // [230] f32
    float* out = (float*)d_out;                   // [2048,690] f32
    unsigned short* Wpk = (unsigned short*)d_ws;  // 245760 B

    pack_w_kernel<<<60, 256, 0, stream>>>(W, Wpk);
    pcnn_mfma<<<B_SZ * 2, 256, 0, stream>>>(Xea, Xmask, Wpk, bias, out);
}

// Round 3
// 267.160 us; speedup vs baseline: 1.8332x; 1.1025x over previous
//
#include <hip/hip_runtime.h>
#include <hip/hip_bf16.h>
#include <math.h>

// PCNN fused: Conv1d(k=3,pad=1) -> masked piecewise max-pool -> tanh
// R11: R8 skeleton (verified tile/frag/epilogue) + two latency fixes:
//  (1) branch-free deep-issued X staging (clamped addrs, zero-selects,
//      store-only guard) -> loads cluster instead of 5 serialized chains.
//  (2) B operand staged via global_load_lds into a 2x16KB LDS double buffer
//      (Wpk chunk kk is contiguous 16KB), issued 1 chunk ahead; consumed by
//      conflict-free ds_read_b128. Frees the 32-VGPR register B path.
//  Occupancy unchanged (2 blocks/CU, 16 waves); win = less stall per wave.

#define B_SZ   2048
#define L_SEQ  128
#define C_INCH 150
#define H_OUT  230
#define RS     152      // row stride in bf16 (304 B); 152 = 19*8
#define NROW   129      // rows l=-1..127; l=128 halo remapped to row 0 (both zero)
#define NS8    2451     // short8s per tile = NROW*RS/8

typedef __attribute__((ext_vector_type(8))) short short8;   // 8 bf16
typedef __attribute__((ext_vector_type(4))) float float4v;  // mfma acc

static __device__ __forceinline__ unsigned short f2bf(float f) {
    union { float f; unsigned u; } x{f};
    unsigned r = (x.u + 0x7FFFu + ((x.u >> 16) & 1u)) >> 16;  // RNE
    return (unsigned short)r;
}

static __device__ __forceinline__ unsigned cvt2(float2 f) {
    __hip_bfloat162 h = __float22bfloat162_rn(f);   // v_cvt_pk_bf16_f32
    union { __hip_bfloat162 h; unsigned u; } c{h};
    return c.u;
}

static __device__ __forceinline__ float tanh_fast_pos(float v) {
    float e = __expf(2.0f * v);
    return 1.0f - 2.0f / (e + 1.0f);
}

// async global->LDS, 16B per lane; lds base must be wave-uniform
static __device__ __forceinline__ void gl_lds16(const void* g, void* l) {
    __builtin_amdgcn_global_load_lds(
        (const __attribute__((address_space(1))) unsigned int*)g,
        (__attribute__((address_space(3))) unsigned int*)l, 16, 0, 0);
}

// Pack W[h][c][k] fp32 -> Wpk fragment order (verified R4-R8):
//   kk = k*5+kc, ht = h/16, lane = q*16+c15
//   Wpk[((kk*16+ht)*64+lane)*8 + e] = bf16(W[ht*16+c15][kc*32+q*8+e][k])
// Chunk kk occupies a contiguous 16384B block: [kk*8192, (kk+1)*8192) shorts.
__global__ void pack_w_kernel(const float* __restrict__ W,
                              unsigned short* __restrict__ Wpk) {
    int t = blockIdx.x * 256 + threadIdx.x;       // < 15360
    int kk   = t >> 10;
    int rem  = t & 1023;
    int ht   = rem >> 6;
    int lane = rem & 63;
    int q    = lane >> 4;
    int c15  = lane & 15;
    int k    = kk / 5;
    int kc   = kk - k * 5;
    int h    = ht * 16 + c15;
    int cb   = kc * 32 + q * 8;
    unsigned short v[8];
    #pragma unroll
    for (int e = 0; e < 8; ++e) {
        int c = cb + e;
        float f = (h < H_OUT && c < C_INCH) ? W[h * 450 + c * 3 + k] : 0.0f;
        v[e] = f2bf(f);
    }
    *(short8*)(Wpk + (size_t)t * 8) = *(short8*)v;
}

__global__ void __launch_bounds__(512, 4)
pcnn_mfma(const float* __restrict__ Xea, const int* __restrict__ Xmask,
          const unsigned short* __restrict__ Wpk,
          const float* __restrict__ bias, float* __restrict__ out) {
    __shared__ __align__(16) unsigned short sX[NROW * RS];      // 39216 B
    __shared__ __align__(16) float sSel[L_SEQ * 3];             // 1536 B
    __shared__ __align__(1024) unsigned char sB[2 * 16384];     // 32768 B

    const int b    = blockIdx.x;
    const int tid  = threadIdx.x;
    const int wv   = tid >> 6;        // 0..7
    const int lane = tid & 63;
    const int q    = lane >> 4;
    const int c15  = lane & 15;
    const int mh   = wv & 1;          // m-half: l offset 64*mh
    const int nh   = wv >> 1;         // n-quarter: h offset 64*nh (0..3)

    // B-stage addressing: 16KB chunk / 8 waves = 2KB per wave = 2 instrs
    const char* wsrc = (const char*)Wpk;
    const int ub = wv * 2048;             // wave-uniform byte offset in chunk
    const int lo = ub + lane * 16;        // per-lane global byte offset

    // ---- issue B0 stage first (async HW queue, no registers) ----
    gl_lds16(wsrc + lo,        (char*)sB + ub);
    gl_lds16(wsrc + lo + 1024, (char*)sB + ub + 1024);

    // ---- X staging: branch-free deep issue ----
    // t indexes short8s: row = t/19 (l = row-1), j = t%19 covers cols 8j..8j+7.
    // row 0 = zero halo. Cols 150,151 zero. Loads unconditional (clamped);
    // halo/pad handled by zero-selects; only the LDS store is guarded.
    const float* xb = Xea + (size_t)b * (L_SEQ * C_INCH);
    float2 pl[5][4];
    #pragma unroll
    for (int it = 0; it < 5; ++it) {
        const int t   = it * 512 + tid;
        const int tc  = (t < NS8) ? t : (NS8 - 1);
        const int row = tc / 19;
        const int j   = tc - row * 19;
        const int rm1 = (row > 0) ? (row - 1) : 0;
        const float* s = xb + rm1 * C_INCH + j * 8;
        pl[it][0] = *(const float2*)(s);
        pl[it][1] = *(const float2*)(s + 2);
        pl[it][2] = *(const float2*)(s + 4);
        // j=18: cols 150,151 don't exist; load dup of 148,149 (in-bounds),
        // zeroed below.
        pl[it][3] = *(const float2*)(s + ((j < 18) ? 6 : 4));
    }

    // mask -> piece selectors {0, -1e30}
    if (tid < L_SEQ) {
        int mv = Xmask[(size_t)b * L_SEQ + tid];
        sSel[tid * 3 + 0] = (mv == 1) ? 0.0f : -1e30f;
        sSel[tid * 3 + 1] = (mv == 2) ? 0.0f : -1e30f;
        sSel[tid * 3 + 2] = (mv == 3) ? 0.0f : -1e30f;
    }

    #pragma unroll
    for (int it = 0; it < 5; ++it) {
        const int t   = it * 512 + tid;
        const int tc  = (t < NS8) ? t : (NS8 - 1);
        const int row = tc / 19;
        const int j   = tc - row * 19;
        uint4 u;
        u.x = cvt2(pl[it][0]);
        u.y = cvt2(pl[it][1]);
        u.z = cvt2(pl[it][2]);
        u.w = cvt2(pl[it][3]);
        const bool z = (row == 0);             // halo row -> zeros
        u.x = z ? 0u : u.x;
        u.y = z ? 0u : u.y;
        u.z = z ? 0u : u.z;
        u.w = (z || j == 18) ? 0u : u.w;       // pad cols 150,151 -> zero
        if (t < NS8) *(uint4*)(sX + (size_t)t * 8) = u;
    }

    __syncthreads();   // X tile + B0 ready (syncthreads drains vmcnt)

    // ---- MFMA: 15 K-chunks of 32; B via LDS double buffer ----
    float4v acc[4][4];
    #pragma unroll
    for (int mi = 0; mi < 4; ++mi)
        #pragma unroll
        for (int nj = 0; nj < 4; ++nj)
            acc[mi][nj] = (float4v){0.f, 0.f, 0.f, 0.f};

    const unsigned short* a0p = sX + (mh * 64 + c15) * RS + q * 8;
    // l=128 halo: row mh*64+c15+mi*16+k == 129 only at (mh=1,mi=3,c15=15,k=2);
    // remap to row 0 (zeros).
    const unsigned short* a3p2 = (mh == 1 && c15 == 15) ? (a0p - 129 * RS) : a0p;

    // per-wave B fragment offsets within a 16KB chunk buffer
    const int bfo = (nh * 4) * 1024 + lane * 16;   // bytes

    #pragma unroll
    for (int kk = 0; kk < 15; ++kk) {
        const int buf = kk & 1;
        // stage next chunk into the other slot (issued early, lands by the
        // barrier at the end of this chunk; vmcnt(0) there is near-free)
        if (kk < 14) {
            const char* src = wsrc + (size_t)(kk + 1) * 16384;
            char* dst = (char*)sB + (buf ^ 1) * 16384;
            gl_lds16(src + lo,        dst + ub);
            gl_lds16(src + lo + 1024, dst + ub + 1024);
        }
        const int k  = kk / 5;
        const int kc = kk - k * 5;

        const char* bbase = (const char*)sB + buf * 16384 + bfo;
        short8 bfrag[4];
        #pragma unroll
        for (int nj = 0; nj < 4; ++nj)
            bfrag[nj] = *(const short8*)(bbase + nj * 1024);

        short8 a[4];
        #pragma unroll
        for (int mi = 0; mi < 4; ++mi) {
            const unsigned short* base = (mi == 3 && k == 2) ? a3p2 : a0p;
            a[mi] = *(const short8*)(base + (mi * 16 + k) * RS + kc * 32);
        }
        #pragma unroll
        for (int mi = 0; mi < 4; ++mi)
            #pragma unroll
            for (int nj = 0; nj < 4; ++nj)
                acc[mi][nj] = __builtin_amdgcn_mfma_f32_16x16x32_bf16(
                    a[mi], bfrag[nj], acc[mi][nj], 0, 0, 0);

        if (kk < 14) __syncthreads();   // flip buffers; next chunk ready
    }

    // ---- Epilogue: selector-add masked max (bias deferred) ----
    // C/D layout: col(h)=c15, row(l in frag)=q*4+r
    float pz[4][3];
    #pragma unroll
    for (int nj = 0; nj < 4; ++nj)
        #pragma unroll
        for (int p = 0; p < 3; ++p) pz[nj][p] = -1e30f;

    #pragma unroll
    for (int mi = 0; mi < 4; ++mi) {
        const int l0 = mh * 64 + mi * 16 + q * 4;            // mult of 4
        const float4v* sp = (const float4v*)(sSel + l0 * 3); // 48B, 16B-aligned
        const float4v s0 = sp[0], s1 = sp[1], s2 = sp[2];
        const float sl[12] = {s0.x, s0.y, s0.z, s0.w, s1.x, s1.y,
                              s1.z, s1.w, s2.x, s2.y, s2.z, s2.w};
        #pragma unroll
        for (int nj = 0; nj < 4; ++nj)
            #pragma unroll
            for (int r = 0; r < 4; ++r) {
                const float y = acc[mi][nj][r];
                pz[nj][0] = fmaxf(pz[nj][0], y + sl[r * 3 + 0]);
                pz[nj][1] = fmaxf(pz[nj][1], y + sl[r * 3 + 1]);
                pz[nj][2] = fmaxf(pz[nj][2], y + sl[r * 3 + 2]);
            }
    }

    __syncthreads();   // all sX reads done -> alias partials onto sX
    float* sP = (float*)sX;   // [mh][h 0..255][3] = 1536 floats

    #pragma unroll
    for (int nj = 0; nj < 4; ++nj) {
        float p0 = pz[nj][0], p1 = pz[nj][1], p2 = pz[nj][2];
        p0 = fmaxf(p0, __shfl_xor(p0, 16, 64));
        p1 = fmaxf(p1, __shfl_xor(p1, 16, 64));
        p2 = fmaxf(p2, __shfl_xor(p2, 16, 64));
        p0 = fmaxf(p0, __shfl_xor(p0, 32, 64));
        p1 = fmaxf(p1, __shfl_xor(p1, 32, 64));
        p2 = fmaxf(p2, __shfl_xor(p2, 32, 64));
        if (q == 0) {
            const int hl = nh * 64 + nj * 16 + c15;          // 0..255
            float* d = sP + (mh * 256 + hl) * 3;
            d[0] = p0; d[1] = p1; d[2] = p2;
        }
    }
    __syncthreads();

    // Combine m-halves, add bias, clamp 0, tanh, store
    for (int t = tid; t < 768; t += 512) {
        const int h = t / 3;
        const int p = t - h * 3;
        if (h < H_OUT) {
            float v = fmaxf(sP[h * 3 + p], sP[(256 + h) * 3 + p]);
            v = fmaxf(0.0f, v + bias[h]);
            out[(size_t)b * (3 * H_OUT) + h * 3 + p] = tanh_fast_pos(v);
        }
    }
}

extern "C" void kernel_launch(void* const* d_in, const int* in_sizes, int n_in,
                              void* d_out, int out_size, void* d_ws, size_t ws_size,
                              hipStream_t stream) {
    const float* Xea   = (const float*)d_in[0];   // [2048,128,150] f32
    const int*   Xmask = (const int*)d_in[1];     // [2048,128] i32
    const float* W     = (const float*)d_in[2];   // [230,150,3] f32
    const float* bias  = (const float*)d_in[3];   // [230] f32
    float* out = (float*)d_out;                   // [2048,690] f32
    unsigned short* Wpk = (unsigned short*)d_ws;  // 245760 B

    pack_w_kernel<<<60, 256, 0, stream>>>(W, Wpk);
    pcnn_mfma<<<B_SZ, 512, 0, stream>>>(Xea, Xmask, Wpk, bias, out);
}

// Round 4
// 256.287 us; speedup vs baseline: 1.9110x; 1.0424x over previous
//
#include <hip/hip_runtime.h>
#include <hip/hip_bf16.h>
#include <math.h>

// PCNN fused: Conv1d(k=3,pad=1) -> masked piecewise max-pool -> tanh
// R12: barrier-free K-loop (R8's good half) + R11's branch-free staging.
//  - B operand in registers, two alternating frag sets bb[kk&1] under full
//    unroll (no bc=bn copies); chunk kk+1 loads issued at head of chunk kk.
//  - NO __syncthreads in the K-loop: waves free-run, cross-wave TLP hides
//    per-wave L2 latency (R11's 14 barrier-drains removed).
//  - sched_barrier(0) per iteration bounds load hoisting (reg pressure);
//    s_setprio(1) around each 16-MFMA cluster (waves now role-diverse).
//  - launch_bounds(512,4) pins regs <=128 (64 VGPR + 64 AGPR, R8-proven).
//  - Staging / tile layout / halo remap / epilogue identical to R11.

#define B_SZ   2048
#define L_SEQ  128
#define C_INCH 150
#define H_OUT  230
#define RS     152      // row stride in bf16 (304 B); 152 = 19*8
#define NROW   129      // rows l=-1..127; l=128 halo remapped to row 0 (both zero)
#define NS8    2451     // short8s per tile = NROW*RS/8

typedef __attribute__((ext_vector_type(8))) short short8;   // 8 bf16
typedef __attribute__((ext_vector_type(4))) float float4v;  // mfma acc

static __device__ __forceinline__ unsigned short f2bf(float f) {
    union { float f; unsigned u; } x{f};
    unsigned r = (x.u + 0x7FFFu + ((x.u >> 16) & 1u)) >> 16;  // RNE
    return (unsigned short)r;
}

static __device__ __forceinline__ unsigned cvt2(float2 f) {
    __hip_bfloat162 h = __float22bfloat162_rn(f);   // v_cvt_pk_bf16_f32
    union { __hip_bfloat162 h; unsigned u; } c{h};
    return c.u;
}

static __device__ __forceinline__ float tanh_fast_pos(float v) {
    float e = __expf(2.0f * v);
    return 1.0f - 2.0f / (e + 1.0f);
}

// Pack W[h][c][k] fp32 -> Wpk fragment order (verified R4-R11):
//   kk = k*5+kc, ht = h/16, lane = q*16+c15
//   Wpk[((kk*16+ht)*64+lane)*8 + e] = bf16(W[ht*16+c15][kc*32+q*8+e][k])
__global__ void pack_w_kernel(const float* __restrict__ W,
                              unsigned short* __restrict__ Wpk) {
    int t = blockIdx.x * 256 + threadIdx.x;       // < 15360
    int kk   = t >> 10;
    int rem  = t & 1023;
    int ht   = rem >> 6;
    int lane = rem & 63;
    int q    = lane >> 4;
    int c15  = lane & 15;
    int k    = kk / 5;
    int kc   = kk - k * 5;
    int h    = ht * 16 + c15;
    int cb   = kc * 32 + q * 8;
    unsigned short v[8];
    #pragma unroll
    for (int e = 0; e < 8; ++e) {
        int c = cb + e;
        float f = (h < H_OUT && c < C_INCH) ? W[h * 450 + c * 3 + k] : 0.0f;
        v[e] = f2bf(f);
    }
    *(short8*)(Wpk + (size_t)t * 8) = *(short8*)v;
}

__global__ void __launch_bounds__(512, 4)
pcnn_mfma(const float* __restrict__ Xea, const int* __restrict__ Xmask,
          const unsigned short* __restrict__ Wpk,
          const float* __restrict__ bias, float* __restrict__ out) {
    __shared__ __align__(16) unsigned short sX[NROW * RS];   // 39216 B
    __shared__ __align__(16) float sSel[L_SEQ * 3];          // 1536 B (tot 40752)

    const int b    = blockIdx.x;
    const int tid  = threadIdx.x;
    const int wv   = tid >> 6;        // 0..7
    const int lane = tid & 63;
    const int q    = lane >> 4;
    const int c15  = lane & 15;
    const int mh   = wv & 1;          // m-half: l offset 64*mh
    const int nh   = wv >> 1;         // n-quarter: h offset 64*nh (0..3)

    const unsigned short* wp = Wpk + ((size_t)(nh * 4) * 64 + lane) * 8;

    // ---- preload B chunk 0 into set 0 (deep issue, before X staging) ----
    short8 bb[2][4];
    #pragma unroll
    for (int nj = 0; nj < 4; ++nj)
        bb[0][nj] = *(const short8*)(wp + nj * 512);

    // ---- X staging: branch-free deep issue (verified R11) ----
    // t indexes short8s: row = t/19 (l = row-1), j = t%19 covers cols 8j..8j+7.
    // row 0 = zero halo. Cols 150,151 zero. Loads unconditional (clamped);
    // halo/pad handled by zero-selects; only the LDS store is guarded.
    const float* xb = Xea + (size_t)b * (L_SEQ * C_INCH);
    float2 pl[5][4];
    #pragma unroll
    for (int it = 0; it < 5; ++it) {
        const int t   = it * 512 + tid;
        const int tc  = (t < NS8) ? t : (NS8 - 1);
        const int row = tc / 19;
        const int j   = tc - row * 19;
        const int rm1 = (row > 0) ? (row - 1) : 0;
        const float* s = xb + rm1 * C_INCH + j * 8;
        pl[it][0] = *(const float2*)(s);
        pl[it][1] = *(const float2*)(s + 2);
        pl[it][2] = *(const float2*)(s + 4);
        // j=18: cols 150,151 don't exist; load dup of 148,149 (in-bounds),
        // zeroed below.
        pl[it][3] = *(const float2*)(s + ((j < 18) ? 6 : 4));
    }

    // mask -> piece selectors {0, -1e30}
    if (tid < L_SEQ) {
        int mv = Xmask[(size_t)b * L_SEQ + tid];
        sSel[tid * 3 + 0] = (mv == 1) ? 0.0f : -1e30f;
        sSel[tid * 3 + 1] = (mv == 2) ? 0.0f : -1e30f;
        sSel[tid * 3 + 2] = (mv == 3) ? 0.0f : -1e30f;
    }

    #pragma unroll
    for (int it = 0; it < 5; ++it) {
        const int t   = it * 512 + tid;
        const int tc  = (t < NS8) ? t : (NS8 - 1);
        const int row = tc / 19;
        const int j   = tc - row * 19;
        uint4 u;
        u.x = cvt2(pl[it][0]);
        u.y = cvt2(pl[it][1]);
        u.z = cvt2(pl[it][2]);
        u.w = cvt2(pl[it][3]);
        const bool z = (row == 0);             // halo row -> zeros
        u.x = z ? 0u : u.x;
        u.y = z ? 0u : u.y;
        u.z = z ? 0u : u.z;
        u.w = (z || j == 18) ? 0u : u.w;       // pad cols 150,151 -> zero
        if (t < NS8) *(uint4*)(sX + (size_t)t * 8) = u;
    }

    __syncthreads();   // X tile ready; only barrier before the epilogue

    // ---- MFMA: 15 K-chunks of 32; B in registers, alternating sets ----
    float4v acc[4][4];
    #pragma unroll
    for (int mi = 0; mi < 4; ++mi)
        #pragma unroll
        for (int nj = 0; nj < 4; ++nj)
            acc[mi][nj] = (float4v){0.f, 0.f, 0.f, 0.f};

    const unsigned short* a0p = sX + (mh * 64 + c15) * RS + q * 8;
    // l=128 halo: row mh*64+c15+mi*16+k == 129 only at (mh=1,mi=3,c15=15,k=2);
    // remap to row 0 (zeros).
    const unsigned short* a3p2 = (mh == 1 && c15 == 15) ? (a0p - 129 * RS) : a0p;

    #pragma unroll
    for (int kk = 0; kk < 15; ++kk) {
        const int cur = kk & 1;
        // issue next chunk's B loads (consumed after this chunk's MFMAs;
        // compiler's vmcnt wait lands behind the 16-MFMA cluster)
        if (kk < 14) {
            #pragma unroll
            for (int nj = 0; nj < 4; ++nj)
                bb[cur ^ 1][nj] =
                    *(const short8*)(wp + (size_t)(kk + 1) * 8192 + nj * 512);
        }
        const int k  = kk / 5;
        const int kc = kk - k * 5;
        short8 a[4];
        #pragma unroll
        for (int mi = 0; mi < 4; ++mi) {
            const unsigned short* base = (mi == 3 && k == 2) ? a3p2 : a0p;
            a[mi] = *(const short8*)(base + (mi * 16 + k) * RS + kc * 32);
        }
        __builtin_amdgcn_s_setprio(1);
        #pragma unroll
        for (int mi = 0; mi < 4; ++mi)
            #pragma unroll
            for (int nj = 0; nj < 4; ++nj)
                acc[mi][nj] = __builtin_amdgcn_mfma_f32_16x16x32_bf16(
                    a[mi], bb[cur][nj], acc[mi][nj], 0, 0, 0);
        __builtin_amdgcn_s_setprio(0);
        // bound cross-iteration hoisting (register pressure), keep per-chunk
        // issue cadence
        __builtin_amdgcn_sched_barrier(0);
    }

    // ---- Epilogue: selector-add masked max (bias deferred) ----
    // C/D layout: col(h)=c15, row(l in frag)=q*4+r
    float pz[4][3];
    #pragma unroll
    for (int nj = 0; nj < 4; ++nj)
        #pragma unroll
        for (int p = 0; p < 3; ++p) pz[nj][p] = -1e30f;

    #pragma unroll
    for (int mi = 0; mi < 4; ++mi) {
        const int l0 = mh * 64 + mi * 16 + q * 4;            // mult of 4
        const float4v* sp = (const float4v*)(sSel + l0 * 3); // 48B, 16B-aligned
        const float4v s0 = sp[0], s1 = sp[1], s2 = sp[2];
        const float sl[12] = {s0.x, s0.y, s0.z, s0.w, s1.x, s1.y,
                              s1.z, s1.w, s2.x, s2.y, s2.z, s2.w};
        #pragma unroll
        for (int nj = 0; nj < 4; ++nj)
            #pragma unroll
            for (int r = 0; r < 4; ++r) {
                const float y = acc[mi][nj][r];
                pz[nj][0] = fmaxf(pz[nj][0], y + sl[r * 3 + 0]);
                pz[nj][1] = fmaxf(pz[nj][1], y + sl[r * 3 + 1]);
                pz[nj][2] = fmaxf(pz[nj][2], y + sl[r * 3 + 2]);
            }
    }

    __syncthreads();   // all sX reads done -> alias partials onto sX
    float* sP = (float*)sX;   // [mh][h 0..255][3] = 1536 floats

    #pragma unroll
    for (int nj = 0; nj < 4; ++nj) {
        float p0 = pz[nj][0], p1 = pz[nj][1], p2 = pz[nj][2];
        p0 = fmaxf(p0, __shfl_xor(p0, 16, 64));
        p1 = fmaxf(p1, __shfl_xor(p1, 16, 64));
        p2 = fmaxf(p2, __shfl_xor(p2, 16, 64));
        p0 = fmaxf(p0, __shfl_xor(p0, 32, 64));
        p1 = fmaxf(p1, __shfl_xor(p1, 32, 64));
        p2 = fmaxf(p2, __shfl_xor(p2, 32, 64));
        if (q == 0) {
            const int hl = nh * 64 + nj * 16 + c15;          // 0..255
            float* d = sP + (mh * 256 + hl) * 3;
            d[0] = p0; d[1] = p1; d[2] = p2;
        }
    }
    __syncthreads();

    // Combine m-halves, add bias, clamp 0, tanh, store
    for (int t = tid; t < 768; t += 512) {
        const int h = t / 3;
        const int p = t - h * 3;
        if (h < H_OUT) {
            float v = fmaxf(sP[h * 3 + p], sP[(256 + h) * 3 + p]);
            v = fmaxf(0.0f, v + bias[h]);
            out[(size_t)b * (3 * H_OUT) + h * 3 + p] = tanh_fast_pos(v);
        }
    }
}

extern "C" void kernel_launch(void* const* d_in, const int* in_sizes, int n_in,
                              void* d_out, int out_size, void* d_ws, size_t ws_size,
                              hipStream_t stream) {
    const float* Xea   = (const float*)d_in[0];   // [2048,128,150] f32
    const int*   Xmask = (const int*)d_in[1];     // [2048,128] i32
    const float* W     = (const float*)d_in[2];   // [230,150,3] f32
    const float* bias  = (const float*)d_in[3];   // [230] f32
    float* out = (float*)d_out;                   // [2048,690] f32
    unsigned short* Wpk = (unsigned short*)d_ws;  // 245760 B

    pack_w_kernel<<<60, 256, 0, stream>>>(W, Wpk);
    pcnn_mfma<<<B_SZ, 512, 0, stream>>>(Xea, Xmask, Wpk, bias, out);
}